// Round 9
// baseline (326.261 us; speedup 1.0000x reference)
//
#include <hip/hip_runtime.h>
#include <hip/hip_bf16.h>

typedef __attribute__((ext_vector_type(8))) short short8;
typedef __attribute__((ext_vector_type(4))) float f32x4;
typedef __attribute__((ext_vector_type(4))) float float4v;
typedef __attribute__((ext_vector_type(4))) unsigned short ushort4v;

// RNE float -> bf16 payload
__device__ __forceinline__ unsigned short f2bf(float f) {
    union { float f; unsigned u; } x; x.f = f;
    unsigned r = x.u + 0x7FFFu + ((x.u >> 16) & 1u);
    return (unsigned short)(r >> 16);
}

// C[k][n] = s(k) * cos(pi * k * (2n+1) / (2N)), N = 512, ortho norm.
__global__ __launch_bounds__(256) void make_dct_mat(unsigned short* __restrict__ Cm) {
    int idx = blockIdx.x * 256 + threadIdx.x;     // 0 .. 512*512-1
    int k = idx >> 9;
    int n = idx & 511;
    int m = (k * (2 * n + 1)) & 2047;             // mod 4N (N=512)
    float ang = (3.14159265358979323846f / 1024.0f) * (float)m;
    float s = (k == 0) ? 0.04419417382415922f : 0.0625f;  // 1/sqrt(512), sqrt(2/512)
    Cm[idx] = f2bf(s * cosf(ang));
}

#define GLD16(g, l) __builtin_amdgcn_global_load_lds( \
    (const __attribute__((address_space(1))) void*)(g), \
    (__attribute__((address_space(3))) void*)(l), 16, 0, 0)

// D[img] = A * B[img]^T  (512x512 row-major per image).
// Block tile: BM=512 (all output rows; A = C matrix, L2-hot) x BN=64.
// B panel (X or T') read from memory exactly once. 76 KB LDS -> 2 blocks/CU.
// 8 waves, wave tile 64x64 (wave wid owns rows [wid*64,+64), all 64 cols).
// A: 2-slot dbuf (distance-1 prefetch from L2); B: 3-slot ring (distance-2,
// HBM). One barrier/K-step, counted vmcnt (B's prefetch stays in flight).
// LDS layouts: proven zero-conflict 16B-slot XOR (slotL = slotG ^ ((row>>1)&3)).
template <bool B_IS_F32, bool OUT_F32>
__device__ __forceinline__ void dct_gemm_body(
    const unsigned short* __restrict__ A,
    const void* __restrict__ Ball,
    void* __restrict__ Dall)
{
    __shared__ unsigned short As[2][4][128 * 32];   // 64 KB (4 msub of [128][32])
    __shared__ unsigned short Bs[3][64 * 32];       // 12 KB

    // XCD-bijective swizzle (2048 % 8 == 0).
    int wg  = blockIdx.x;
    int cpx = gridDim.x >> 3;
    int swz = (wg & 7) * cpx + (wg >> 3);
    int img = swz >> 3;
    int C0  = (swz & 7) * 64;     // output-column strip

    int t    = threadIdx.x;       // 0..511
    int lane = t & 63;
    int wid  = t >> 6;            // 0..7 -> rows [wid*64, +64)

    f32x4 acc[4][4] = {};         // 64 VGPR

    const size_t imgoff = (size_t)img * (512 * 512);

    // ---- A staging: per sub-tile [128][32], thread t -> (row=t>>2, slotL=t&3),
    // source slot pre-XORed (proven zero-conflict layout). 4 GLD16 / thread.
    const int aslotG = ((t & 3) ^ ((t >> 3) & 3)) * 8;
    const unsigned short* gA = A + (size_t)(t >> 2) * 512 + aslotG;
    auto stageA = [&](int sl, int kk) {
        #pragma unroll
        for (int ms = 0; ms < 4; ++ms)
            GLD16(gA + (size_t)ms * 128 * 512 + kk, &As[sl][ms][t * 8]);
    };

    // ---- B staging ----
    // s2 (bf16): tile [64][32] = 4 KB = 256 x 16B; threads 256..511 duplicate
    // (same dest, same data - benign) so vmcnt is wave-uniform. 1 GLD16 / thread.
    const unsigned short* gB16 = nullptr;
    const float* gBf = nullptr;
    if constexpr (B_IS_F32) {
        // s1 (fp32): thread t owns LDS 8B-granule t: row=t>>3, gL=t&7,
        // sL=gL>>1, half=gL&1; global slot sG = sL ^ ((row>>1)&3).
        const int gG = ((((t & 7) >> 1) ^ ((t >> 4) & 3)) * 2 + (t & 1));
        gBf = (const float*)Ball + imgoff + (size_t)(C0 + (t >> 3)) * 512 + gG * 4;
    } else {
        const int tt = t & 255;
        gB16 = (const unsigned short*)Ball + imgoff
             + (size_t)(C0 + (tt >> 2)) * 512 + ((tt & 3) ^ ((tt >> 3) & 3)) * 8;
    }
    auto stageB16 = [&](int sl, int kk) {
        GLD16(gB16 + kk, &Bs[sl][(t & 255) * 8]);
    };
    float4v breg[2];
    auto loadBf32 = [&](int which, int kk) {   // 1 vmem load / thread
        breg[which] = *(const float4v*)(gBf + kk);
    };
    auto writeBf32 = [&](int sl, int which) {  // 1 ushort4 ds_write / thread
        ushort4v p;
        p.x = f2bf(breg[which].x); p.y = f2bf(breg[which].y);
        p.z = f2bf(breg[which].z); p.w = f2bf(breg[which].w);
        *(ushort4v*)(&Bs[sl][(t >> 3) * 32 + ((t & 7) >> 1) * 8 + (t & 1) * 4]) = p;
    };

    auto compute = [&](int asl, int bsl) {
        const int roff = ((lane >> 4) ^ ((lane >> 1) & 3)) * 8;   // proven read swizzle
        short8 av[4], bv[4];
        #pragma unroll
        for (int m = 0; m < 4; ++m)
            av[m] = *(const short8*)(&As[asl][wid >> 1]
                        [((wid & 1) * 64 + m * 16 + (lane & 15)) * 32 + roff]);
        #pragma unroll
        for (int n = 0; n < 4; ++n)
            bv[n] = *(const short8*)(&Bs[bsl][(n * 16 + (lane & 15)) * 32 + roff]);
        __builtin_amdgcn_s_setprio(1);
        #pragma unroll
        for (int m = 0; m < 4; ++m)
            #pragma unroll
            for (int n = 0; n < 4; ++n)
                acc[m][n] = __builtin_amdgcn_mfma_f32_16x16x32_bf16(
                                av[m], bv[n], acc[m][n], 0, 0, 0);
        __builtin_amdgcn_s_setprio(0);
    };

    // ---- prologue: A(0); B(0); B(1). queue: [A0 x4, B0, B1] ----
    stageA(0, 0);
    if constexpr (B_IS_F32) { loadBf32(0, 0); loadBf32(1, 32); }
    else                    { stageB16(0, 0); stageB16(1, 32); }
    // need A0 + B0; keep B1 outstanding
    asm volatile("s_waitcnt vmcnt(1)" ::: "memory");
    if constexpr (B_IS_F32) {
        writeBf32(0, 0);
        asm volatile("s_waitcnt lgkmcnt(0)" ::: "memory");
    }
    asm volatile("s_barrier" ::: "memory");

    // ---- main loop: step kt issues A(kt+1) [dist 1, L2] and B(kt+2) [dist 2] ----
    #pragma unroll
    for (int kt = 0; kt < 16; ++kt) {
        if (kt < 15) stageA((kt + 1) & 1, (kt + 1) * 32);
        if (kt < 14) {
            if constexpr (B_IS_F32) loadBf32(kt & 1, (kt + 2) * 32);  // breg[(kt+2)&1]
            else                    stageB16((kt + 2) % 3, (kt + 2) * 32);
        }
        compute(kt & 1, kt % 3);
        if (kt < 15) {
            // retire [B(kt+1), A(kt+1)x4]; keep B(kt+2) in flight (if issued)
            if (kt < 14) asm volatile("s_waitcnt vmcnt(1)" ::: "memory");
            else         asm volatile("s_waitcnt vmcnt(0)" ::: "memory");
            if constexpr (B_IS_F32) {
                writeBf32((kt + 1) % 3, (kt + 1) & 1);
                asm volatile("s_waitcnt lgkmcnt(0)" ::: "memory");
            }
            asm volatile("s_barrier" ::: "memory");
        }
    }

    // ---- epilogue: row from A-frag, col from B-frag (col=lane&15 convention) ----
    int r0 = wid * 64 + (lane >> 4) * 4;
    int c0 = C0 + (lane & 15);
    if constexpr (OUT_F32) {
        float* D = (float*)Dall + imgoff;
        #pragma unroll
        for (int m = 0; m < 4; ++m)
            #pragma unroll
            for (int n = 0; n < 4; ++n)
                #pragma unroll
                for (int r = 0; r < 4; ++r)
                    D[(size_t)(r0 + m * 16 + r) * 512 + c0 + n * 16] = acc[m][n][r];
    } else {
        unsigned short* D = (unsigned short*)Dall + imgoff;
        #pragma unroll
        for (int m = 0; m < 4; ++m)
            #pragma unroll
            for (int n = 0; n < 4; ++n)
                #pragma unroll
                for (int r = 0; r < 4; ++r)
                    D[(size_t)(r0 + m * 16 + r) * 512 + c0 + n * 16] = f2bf(acc[m][n][r]);
    }
}

__global__ __launch_bounds__(512, 4) void dct_gemm_s1(
    const unsigned short* __restrict__ A, const float* __restrict__ B,
    unsigned short* __restrict__ D) {
    dct_gemm_body<true, false>(A, B, D);
}

__global__ __launch_bounds__(512, 4) void dct_gemm_s2(
    const unsigned short* __restrict__ A, const unsigned short* __restrict__ B,
    float* __restrict__ D) {
    dct_gemm_body<false, true>(A, B, D);
}

extern "C" void kernel_launch(void* const* d_in, const int* in_sizes, int n_in,
                              void* d_out, int out_size, void* d_ws, size_t ws_size,
                              hipStream_t stream) {
    const float* x = (const float*)d_in[0];
    float* out = (float*)d_out;

    // ws layout: [0, 512KB) = C matrix bf16; [1MB, 1MB+128MB) = intermediate T' bf16
    unsigned short* Cm = (unsigned short*)d_ws;
    unsigned short* Tm = (unsigned short*)((char*)d_ws + (1 << 20));

    int nimg = in_sizes[0] / (512 * 512);   // 256

    make_dct_mat<<<dim3(1024), dim3(256), 0, stream>>>(Cm);
    // Stage 1: T'[b] = C * X[b]^T   (B = fp32 -> cvt in regs -> bf16 LDS, out = bf16)
    dct_gemm_s1<<<dim3(nimg * 8), dim3(512), 0, stream>>>(Cm, x, Tm);
    // Stage 2: Y[b] = C * T'[b]^T = C X C^T  (B = bf16 via global_load_lds, out = fp32)
    dct_gemm_s2<<<dim3(nimg * 8), dim3(512), 0, stream>>>(Cm, Tm, out);
}